// Round 13
// baseline (340.985 us; speedup 1.0000x reference)
//
#include <hip/hip_runtime.h>
#include <hip/hip_bf16.h>
#include <math.h>

typedef __hip_bfloat16 bf16;
typedef __attribute__((ext_vector_type(8))) short short8v;   // 8 bf16 = 4 VGPRs (MFMA A/B frag)
typedef __attribute__((ext_vector_type(4))) float f32x4;     // MFMA C/D frag

#define NN 50000
#define EE 800000
#define EPB 4096   // edges per block (hist/scatter)
#define NBK 196    // dst buckets = ceil(NN/256); also blocks for hist/scatter
#define BCAP 6144  // max edges per bucket (mean 4096, sd ~64)

__device__ __forceinline__ float b2f(bf16 v) { return __bfloat162float(v); }
__device__ __forceinline__ float rcp_(float x) { return __builtin_amdgcn_rcpf(x); }
__device__ __forceinline__ float sigmoidf_(float x) { return rcp_(1.0f + __expf(-x)); }
__device__ __forceinline__ float tanhf_(float x) {
    float xx = fminf(fmaxf(x, -15.0f), 15.0f);
    float e = __expf(2.0f * xx);
    return (e - 1.0f) * rcp_(e + 1.0f);
}
__device__ __forceinline__ float leakyf_(float x) { return x > 0.0f ? x : 0.2f * x; }
__device__ __forceinline__ unsigned short f2bf(float f) {
    unsigned u = __float_as_uint(f);
    unsigned r = (u + 0x7FFFu + ((u >> 16) & 1u)) >> 16;
    return (unsigned short)r;
}
__device__ __forceinline__ unsigned pack2(float a, float b) {
    return (unsigned)f2bf(a) | ((unsigned)f2bf(b) << 16);
}
__device__ __forceinline__ float lo_(unsigned u) { return __uint_as_float(u << 16); }
__device__ __forceinline__ float hi_(unsigned u) { return __uint_as_float(u & 0xFFFF0000u); }
__device__ __forceinline__ void split4(float4 v, ushort4& hi, ushort4& lo) {
    hi.x = f2bf(v.x); lo.x = f2bf(v.x - __uint_as_float((unsigned)hi.x << 16));
    hi.y = f2bf(v.y); lo.y = f2bf(v.y - __uint_as_float((unsigned)hi.y << 16));
    hi.z = f2bf(v.z); lo.z = f2bf(v.z - __uint_as_float((unsigned)hi.z << 16));
    hi.w = f2bf(v.w); lo.w = f2bf(v.w - __uint_as_float((unsigned)hi.w << 16));
}

// weight-pool element offsets (fp32 pool in ws)
#define OFF_W1 0
#define OFF_B1 16384
#define OFF_W2 16512
#define OFF_B2 24704
#define OFF_W3 24768
#define OFF_B3 26816
#define OFF_GATW 26848
#define OFF_GAS 27872
#define OFF_GAD 27904
#define OFF_GAB 27936
#define OFF_WIHF 27968
#define OFF_BIHF 36160
#define OFF_BHHF 36416
#define OFF_WIHB 36672
#define OFF_BIHB 44864
#define OFF_BHHB 45120
#define OFF_GAMMA 45376
#define OFF_BETA 45504
#define OFF_FCW 45632
#define OFF_FCB 46912
#define WTOTAL 46922

struct WSrc { const void* p[20]; };

// ---------------- dtype detection ----------------
__global__ void k_detect(const unsigned short* __restrict__ xraw,
                         const unsigned int* __restrict__ eraw, int* __restrict__ flags) {
    __shared__ int f32f, i64f;
    int t = threadIdx.x;
    if (t == 0) { f32f = 0; i64f = 1; }
    __syncthreads();
    for (int i = t; i < 4096; i += 256) {
        unsigned short u = xraw[i];
        int ex = (u >> 7) & 0xFF;
        if (ex >= 0xC0) atomicOr(&f32f, 1);
        if (eraw[2 * i + 1] != 0u) atomicAnd(&i64f, 0);
    }
    __syncthreads();
    if (t == 0) { flags[0] = f32f; flags[1] = i64f; }
}

// ---------------- weight conversion into fp32 pool ----------------
__global__ void k_cvt_w(WSrc srcs, float* __restrict__ dst, const int* __restrict__ flags,
                        int total) {
    constexpr int WOFF[21] = {OFF_W1,   OFF_B1,   OFF_W2,   OFF_B2,   OFF_W3,   OFF_B3,
                              OFF_GATW, OFF_GAS,  OFF_GAD,  OFF_GAB,  OFF_WIHF, OFF_BIHF,
                              OFF_BHHF, OFF_WIHB, OFF_BIHB, OFF_BHHB, OFF_GAMMA, OFF_BETA,
                              OFF_FCW,  OFF_FCB,  WTOTAL};
    int i = blockIdx.x * 256 + threadIdx.x;
    if (i >= total) return;
    int tn = 0;
#pragma unroll
    for (int j = 1; j < 20; ++j)
        if (i >= WOFF[j]) tn = j;
    int local = i - WOFF[tn];
    if (flags[0]) dst[i] = ((const float*)srcs.p[tn])[local];
    else dst[i] = b2f(((const bf16*)srcs.p[tn])[local]);
}

// ---------------- ALL weight hi/lo splits in one kernel ---------------------------------
__global__ void k_prep_all(const float* __restrict__ wp, unsigned short* __restrict__ w1,
                           unsigned short* __restrict__ w2, unsigned short* __restrict__ w3,
                           unsigned short* __restrict__ wgat, unsigned short* __restrict__ wg) {
    int i = blockIdx.x * 256 + threadIdx.x;
    if (i < 16384) {
        int k = i >> 7, col = i & 127;
        float v = wp[OFF_W1 + k * 128 + col];
        unsigned short hi = f2bf(v);
        unsigned short lo = f2bf(v - __uint_as_float((unsigned)hi << 16));
        int kt = k >> 5, kk = k & 31;
        w1[((size_t)(kt * 2 + 0) * 128 + col) * 32 + kk] = hi;
        w1[((size_t)(kt * 2 + 1) * 128 + col) * 32 + kk] = lo;
    } else if (i < 24576) {
        int j = i - 16384;
        int k = j >> 6, col = j & 63;
        float v = wp[OFF_W2 + k * 64 + col];
        unsigned short hi = f2bf(v);
        unsigned short lo = f2bf(v - __uint_as_float((unsigned)hi << 16));
        int kt = k >> 5, kk = k & 31;
        w2[((size_t)(kt * 2 + 0) * 64 + col) * 32 + kk] = hi;
        w2[((size_t)(kt * 2 + 1) * 64 + col) * 32 + kk] = lo;
    } else if (i < 26624) {
        int j = i - 24576;
        int k = j >> 5, col = j & 31;
        float v = wp[OFF_W3 + k * 32 + col];
        unsigned short hi = f2bf(v);
        unsigned short lo = f2bf(v - __uint_as_float((unsigned)hi << 16));
        int kt = k >> 5, kk = k & 31;
        w3[((size_t)(kt * 2 + 0) * 32 + col) * 32 + kk] = hi;
        w3[((size_t)(kt * 2 + 1) * 32 + col) * 32 + kk] = lo;
    } else if (i < 27648) {
        int j = i - 26624;
        int k = j >> 5, col = j & 31;
        float v = wp[OFF_GATW + k * 32 + col];
        unsigned short hi = f2bf(v);
        unsigned short lo = f2bf(v - __uint_as_float((unsigned)hi << 16));
        int kk = k & 31;
        wgat[((size_t)col) * 32 + kk] = hi;
        wgat[((size_t)(32 + col)) * 32 + kk] = lo;
    } else if (i < 39936) {
        int j = i - 27648;
        int dir = j / 6144, r2 = j % 6144;
        int row = r2 >> 5, k = r2 & 31;
        int gate = row >> 6, jj = row & 63;
        int srcrow = jj + (gate == 1 ? 128 : (gate == 2 ? 192 : 0));
        const float* W = wp + (dir ? OFF_WIHB : OFF_WIHF);
        float v = W[(size_t)srcrow * 32 + k];
        unsigned short hi = f2bf(v);
        unsigned short lo = f2bf(v - __uint_as_float((unsigned)hi << 16));
        wg[((size_t)(dir * 2 + 0) * 192 + row) * 32 + k] = hi;
        wg[((size_t)(dir * 2 + 1) * 192 + row) * 32 + k] = lo;
    }
}

// ---------------- bucketed CSR build ----------------
__global__ __launch_bounds__(256) void k_hist(const void* __restrict__ eraw,
                                              unsigned* __restrict__ gh,
                                              const int* __restrict__ flags) {
    __shared__ int h[256];
    int t = threadIdx.x, b = blockIdx.x;
    h[t] = 0;
    __syncthreads();
    int e0 = b * EPB;
    bool i64 = flags[1] != 0;
    for (int i = t; i < EPB; i += 256) {
        int e = e0 + i;
        if (e < EE) {
            int d = i64 ? (int)((const long long*)eraw)[EE + e] : ((const int*)eraw)[EE + e];
            d = min(max(d, 0), NN - 1);
            atomicAdd(&h[d >> 8], 1);
        }
    }
    __syncthreads();
    gh[b * 256 + t] = (unsigned)h[t];
}

// P2a: per-bucket scan over the 196 edge-blocks (256-way block parallelism).
__global__ __launch_bounds__(256) void k_bscan_a(const unsigned* __restrict__ gh,
                                                 unsigned* __restrict__ gh2,
                                                 unsigned* __restrict__ bsum) {
    __shared__ unsigned s[256];
    int b = blockIdx.x;   // bucket
    int t = threadIdx.x;  // edge-block index
    unsigned v = (t < NBK) ? gh[t * 256 + b] : 0u;
    s[t] = v;
    __syncthreads();
    for (int o = 1; o < 256; o <<= 1) {
        unsigned x = (t >= o) ? s[t - o] : 0u;
        __syncthreads();
        s[t] += x;
        __syncthreads();
    }
    if (t < NBK) gh2[t * 256 + b] = s[t] - v;  // exclusive within-bucket offset
    if (t == 255) bsum[b] = s[255];
}

// P2b: scan of 256 bucket totals -> bucket bases (tiny single block)
__global__ __launch_bounds__(256) void k_bscan_b(const unsigned* __restrict__ bsum,
                                                 int* __restrict__ bb, int* __restrict__ rptr) {
    __shared__ int s[256];
    int t = threadIdx.x;
    int v = (int)bsum[t];
    s[t] = v;
    __syncthreads();
    for (int o = 1; o < 256; o <<= 1) {
        int x = (t >= o) ? s[t - o] : 0;
        __syncthreads();
        s[t] += x;
        __syncthreads();
    }
    bb[t] = s[t] - v;  // exclusive bucket base (bb[196] lands on EE)
    if (t == 0) rptr[NN] = EE;
}

__global__ __launch_bounds__(256) void k_scatter(const void* __restrict__ eraw,
                                                 const unsigned* __restrict__ gh2,
                                                 const int* __restrict__ bb,
                                                 int2* __restrict__ ebkt,
                                                 const int* __restrict__ flags) {
    __shared__ unsigned cur[256];
    int t = threadIdx.x, b = blockIdx.x;
    cur[t] = gh2[b * 256 + t] + (unsigned)bb[t];
    __syncthreads();
    int e0 = b * EPB;
    bool i64 = flags[1] != 0;
    for (int i = t; i < EPB; i += 256) {
        int e = e0 + i;
        if (e < EE) {
            int sn, d;
            if (i64) {
                sn = (int)((const long long*)eraw)[e];
                d = (int)((const long long*)eraw)[EE + e];
            } else {
                sn = ((const int*)eraw)[e];
                d = ((const int*)eraw)[EE + e];
            }
            sn = min(max(sn, 0), NN - 1);
            d = min(max(d, 0), NN - 1);
            unsigned pos = atomicAdd(&cur[d >> 8], 1u);
            if (pos < (unsigned)EE) ebkt[pos] = make_int2(sn, d);
        }
    }
}

__global__ __launch_bounds__(256) void k_bucket_csr(const int2* __restrict__ ebkt,
                                                    const int* __restrict__ bb,
                                                    int* __restrict__ rptr,
                                                    float* __restrict__ dis,
                                                    int* __restrict__ csr_src) {
    __shared__ int hist[256];
    __shared__ int excl[256];
    __shared__ int cur[256];
    __shared__ int sorted[BCAP];
    int t = threadIdx.x, b = blockIdx.x;
    int s0 = bb[b], s1 = bb[b + 1];
    int len = min(s1 - s0, BCAP);
    hist[t] = 0;
    __syncthreads();
    for (int i = t; i < len; i += 256) atomicAdd(&hist[ebkt[s0 + i].y & 255], 1);
    __syncthreads();
    int v = hist[t];
    excl[t] = v;
    __syncthreads();
    for (int o = 1; o < 256; o <<= 1) {
        int x = (t >= o) ? excl[t - o] : 0;
        __syncthreads();
        excl[t] += x;
        __syncthreads();
    }
    int loc = excl[t] - v;  // local exclusive offset
    int node = b * 256 + t;
    if (node < NN) {
        rptr[node] = s0 + loc;
        dis[node] = rsqrtf((float)(v + 1));
    }
    cur[t] = loc;
    __syncthreads();
    for (int i = t; i < len; i += 256) {
        int2 p = ebkt[s0 + i];
        int pos = atomicAdd(&cur[p.y & 255], 1);
        if (pos < BCAP) sorted[pos] = p.x;
    }
    __syncthreads();
    for (int i = t; i < len; i += 256) csr_src[s0 + i] = sorted[i];
}

// ---------------- GCN1 via MFMA (both input dtypes, split-precision) --------------------
template <int MODE>
__global__ __launch_bounds__(256) void k_gcn1_mfma(const void* __restrict__ A,
                                                   const unsigned short* __restrict__ wsplit,
                                                   unsigned* __restrict__ C, int n,
                                                   const int* __restrict__ flags,
                                                   const float* __restrict__ dis) {
    if (flags[0] != MODE) return;
    __shared__ unsigned short Ah[64 * 136];                   // 17.4 KB
    __shared__ unsigned short Al[MODE ? 64 * 136 : 4];        // 17.4 KB (MODE 1 only)
    __shared__ unsigned short Wh[128 * 40];                   // 10.2 KB
    __shared__ unsigned short Wl[128 * 40];                   // 10.2 KB
    int t = threadIdx.x;
    int l = t & 63, w = t >> 6;
    int base = blockIdx.x * 64;
    if constexpr (MODE == 0) {
#pragma unroll
        for (int p = 0; p < 4; ++p) {
            int c = p * 256 + t;
            int nd = c >> 4, ko = (c & 15) * 8;
            int node = min(base + nd, n - 1);
            uint4 v = *(const uint4*)((const unsigned short*)A + (size_t)node * 128 + ko);
            *(uint4*)(Ah + nd * 136 + ko) = v;
        }
    } else {
#pragma unroll
        for (int p = 0; p < 8; ++p) {
            int c = p * 256 + t;
            int nd = c >> 5, ko = (c & 31) * 4;
            int node = min(base + nd, n - 1);
            float4 v = *(const float4*)((const float*)A + (size_t)node * 128 + ko);
            ushort4 hi, lo;
            split4(v, hi, lo);
            *(ushort4*)(Ah + nd * 136 + ko) = hi;
            *(ushort4*)(Al + nd * 136 + ko) = lo;
        }
    }
    int wr = (w >> 1) * 32, wc = (w & 1) * 64;
    int lrow = l & 15, lk = (l >> 4) * 8;
    f32x4 acc[2][4];
#pragma unroll
    for (int rb = 0; rb < 2; ++rb)
#pragma unroll
        for (int cb = 0; cb < 4; ++cb) acc[rb][cb] = (f32x4){0.f, 0.f, 0.f, 0.f};
    for (int kt = 0; kt < 4; ++kt) {
        __syncthreads();
#pragma unroll
        for (int p = 0; p < 2; ++p) {
            int c = p * 256 + t;
            int col = c >> 2, ko = (c & 3) * 8;
            *(uint4*)(Wh + col * 40 + ko) =
                *(const uint4*)(wsplit + ((size_t)(kt * 2 + 0) * 128 + col) * 32 + ko);
            *(uint4*)(Wl + col * 40 + ko) =
                *(const uint4*)(wsplit + ((size_t)(kt * 2 + 1) * 128 + col) * 32 + ko);
        }
        __syncthreads();
        short8v ah0 = *(const short8v*)(Ah + (wr + lrow) * 136 + kt * 32 + lk);
        short8v ah1 = *(const short8v*)(Ah + (wr + 16 + lrow) * 136 + kt * 32 + lk);
        short8v al0, al1;
        if constexpr (MODE == 1) {
            al0 = *(const short8v*)(Al + (wr + lrow) * 136 + kt * 32 + lk);
            al1 = *(const short8v*)(Al + (wr + 16 + lrow) * 136 + kt * 32 + lk);
        }
#pragma unroll
        for (int cb = 0; cb < 4; ++cb) {
            int col = wc + cb * 16 + lrow;
            short8v bh = *(const short8v*)(Wh + col * 40 + lk);
            short8v bl = *(const short8v*)(Wl + col * 40 + lk);
            acc[0][cb] = __builtin_amdgcn_mfma_f32_16x16x32_bf16(ah0, bh, acc[0][cb], 0, 0, 0);
            acc[0][cb] = __builtin_amdgcn_mfma_f32_16x16x32_bf16(ah0, bl, acc[0][cb], 0, 0, 0);
            acc[1][cb] = __builtin_amdgcn_mfma_f32_16x16x32_bf16(ah1, bh, acc[1][cb], 0, 0, 0);
            acc[1][cb] = __builtin_amdgcn_mfma_f32_16x16x32_bf16(ah1, bl, acc[1][cb], 0, 0, 0);
            if constexpr (MODE == 1) {
                acc[0][cb] = __builtin_amdgcn_mfma_f32_16x16x32_bf16(al0, bh, acc[0][cb], 0, 0, 0);
                acc[1][cb] = __builtin_amdgcn_mfma_f32_16x16x32_bf16(al1, bh, acc[1][cb], 0, 0, 0);
            }
        }
    }
#pragma unroll
    for (int rb = 0; rb < 2; ++rb) {
#pragma unroll
        for (int reg = 0; reg < 4; ++reg) {
            int row = wr + rb * 16 + (l >> 4) * 4 + reg;
            int node = base + row;
            if (node < n) {
                float sc = dis[node];
                unsigned short* cr = (unsigned short*)C + (size_t)node * 128;
#pragma unroll
                for (int cb = 0; cb < 4; ++cb) {
                    int col = wc + cb * 16 + lrow;
                    cr[col] = f2bf(acc[rb][cb][reg] * sc);
                }
            }
        }
    }
}

// ---------------- FUSED agg128 + GEMM(128->64): h1 never touches HBM -------------------
// 512 threads = 8 waves. Phase 1: wave w aggregates nodes w*8..w*8+7 (full-wave 64-lane
// gather over t' bf16 pairs, identical math to old k_agg128<true> with B1 bias), then
// splits the fp32 result hi/lo straight into the MFMA A-tile LDS. Phase 2: the proven
// mm<128,64,SCALE> MFMA body re-mapped to 8 waves (row-tile w>>2, col-tile w&3) —
// identical MFMA sequence per output element -> bit-identical to the unfused pair.
__global__ __launch_bounds__(512) void k_aggmm1(const unsigned* __restrict__ tin,
                                                const int* __restrict__ rptr,
                                                const int* __restrict__ csr_src,
                                                const float* __restrict__ dis,
                                                const float* __restrict__ bias,
                                                const unsigned short* __restrict__ ws2,
                                                unsigned short* __restrict__ C, int n) {
    __shared__ unsigned short Ah[64 * 136];  // 17.4 KB
    __shared__ unsigned short Al[64 * 136];  // 17.4 KB
    __shared__ unsigned short Wh[64 * 40];   // 5.1 KB
    __shared__ unsigned short Wl[64 * 40];   // 5.1 KB
    int t = threadIdx.x, l = t & 63, w = t >> 6;
    int base = blockIdx.x * 64;
    // ---- phase 1: aggregation (8 nodes per wave, serial)
    float2 bv = *(const float2*)(bias + 2 * l);
    for (int i = 0; i < 8; ++i) {
        int nd = w * 8 + i;
        int node = min(base + nd, n - 1);
        float dd = dis[node];
        float ax, ay;
        {
            unsigned u = tin[(size_t)node * 64 + l];
            ax = lo_(u);
            ay = hi_(u);
        }
        int s = __builtin_amdgcn_readfirstlane(max(0, min(rptr[node], EE)));
        int e = __builtin_amdgcn_readfirstlane(max(s, min(rptr[node + 1], EE)));
        int j = s;
        for (; j + 4 <= e; j += 4) {
            int i0 = csr_src[j], i1 = csr_src[j + 1], i2 = csr_src[j + 2], i3 = csr_src[j + 3];
            unsigned u0 = tin[(size_t)i0 * 64 + l], u1 = tin[(size_t)i1 * 64 + l];
            unsigned u2 = tin[(size_t)i2 * 64 + l], u3 = tin[(size_t)i3 * 64 + l];
            ax += (lo_(u0) + lo_(u1)) + (lo_(u2) + lo_(u3));
            ay += (hi_(u0) + hi_(u1)) + (hi_(u2) + hi_(u3));
        }
        for (; j < e; ++j) {
            unsigned u0 = tin[(size_t)csr_src[j] * 64 + l];
            ax += lo_(u0);
            ay += hi_(u0);
        }
        float vx = fmaxf(ax * dd + bv.x, 0.f);
        float vy = fmaxf(ay * dd + bv.y, 0.f);
        unsigned short hx = f2bf(vx);
        unsigned short hy = f2bf(vy);
        float lx = vx - __uint_as_float((unsigned)hx << 16);
        float ly = vy - __uint_as_float((unsigned)hy << 16);
        *(unsigned*)(Ah + nd * 136 + 2 * l) = (unsigned)hx | ((unsigned)hy << 16);
        *(unsigned*)(Al + nd * 136 + 2 * l) = (unsigned)f2bf(lx) | ((unsigned)f2bf(ly) << 16);
    }
    // ---- phase 2: GEMM (KIN=128, KOUT=64), 8 waves
    int wr = (w >> 2) * 32, wc = (w & 3) * 16;
    int lrow = l & 15, lk = (l >> 4) * 8;
    f32x4 acc0 = (f32x4){0.f, 0.f, 0.f, 0.f};
    f32x4 acc1 = (f32x4){0.f, 0.f, 0.f, 0.f};
    for (int kt = 0; kt < 4; ++kt) {
        __syncthreads();  // kt=0: A-tile complete; kt>0: W reads done
        for (int c = t; c < 256; c += 512) {  // 64 cols x 4 uint4-chunks per buffer
            int col = c >> 2, ko = (c & 3) * 8;
            *(uint4*)(Wh + col * 40 + ko) =
                *(const uint4*)(ws2 + ((size_t)(kt * 2 + 0) * 64 + col) * 32 + ko);
            *(uint4*)(Wl + col * 40 + ko) =
                *(const uint4*)(ws2 + ((size_t)(kt * 2 + 1) * 64 + col) * 32 + ko);
        }
        __syncthreads();
        short8v ah0 = *(const short8v*)(Ah + (wr + lrow) * 136 + kt * 32 + lk);
        short8v ah1 = *(const short8v*)(Ah + (wr + 16 + lrow) * 136 + kt * 32 + lk);
        short8v al0 = *(const short8v*)(Al + (wr + lrow) * 136 + kt * 32 + lk);
        short8v al1 = *(const short8v*)(Al + (wr + 16 + lrow) * 136 + kt * 32 + lk);
        short8v bh = *(const short8v*)(Wh + (wc + lrow) * 40 + lk);
        short8v bl = *(const short8v*)(Wl + (wc + lrow) * 40 + lk);
        acc0 = __builtin_amdgcn_mfma_f32_16x16x32_bf16(ah0, bh, acc0, 0, 0, 0);
        acc0 = __builtin_amdgcn_mfma_f32_16x16x32_bf16(ah0, bl, acc0, 0, 0, 0);
        acc0 = __builtin_amdgcn_mfma_f32_16x16x32_bf16(al0, bh, acc0, 0, 0, 0);
        acc1 = __builtin_amdgcn_mfma_f32_16x16x32_bf16(ah1, bh, acc1, 0, 0, 0);
        acc1 = __builtin_amdgcn_mfma_f32_16x16x32_bf16(ah1, bl, acc1, 0, 0, 0);
        acc1 = __builtin_amdgcn_mfma_f32_16x16x32_bf16(al1, bh, acc1, 0, 0, 0);
    }
#pragma unroll
    for (int rb = 0; rb < 2; ++rb) {
#pragma unroll
        for (int reg = 0; reg < 4; ++reg) {
            int row = wr + rb * 16 + (l >> 4) * 4 + reg;
            int node = base + row;
            if (node < n) {
                float sc = dis[node];
                float v = rb ? acc1[reg] : acc0[reg];
                C[(size_t)node * 64 + wc + lrow] = f2bf(v * sc);
            }
        }
    }
}

// ---------------- generic MFMA GEMM: C(bf16[KOUT]) = A(fp32[KIN]) @ W, split-precision --
template <int KIN, int KOUT, bool SCALE>
__global__ __launch_bounds__(256) void k_mm_mfma(const float* __restrict__ A,
                                                 const unsigned short* __restrict__ wsplit,
                                                 unsigned short* __restrict__ C, int n,
                                                 const float* __restrict__ dis) {
    constexpr int AST = KIN + 8;
    constexpr int KT = KIN / 32;
    constexpr int CB = KOUT / 32;  // col-blocks per wave (KOUT=64 -> 2, 32 -> 1)
    __shared__ unsigned short Ah[64 * AST];
    __shared__ unsigned short Al[64 * AST];
    __shared__ unsigned short Wh[KOUT * 40];
    __shared__ unsigned short Wl[KOUT * 40];
    int t = threadIdx.x;
    int l = t & 63, w = t >> 6;
    int base = blockIdx.x * 64;
#pragma unroll
    for (int p = 0; p < KIN / 16; ++p) {
        int c = p * 256 + t;  // 64*KIN/4 float4 chunks
        int nd = c / (KIN / 4), ko = (c % (KIN / 4)) * 4;
        int node = min(base + nd, n - 1);
        float4 v = *(const float4*)(A + (size_t)node * KIN + ko);
        ushort4 hi, lo;
        split4(v, hi, lo);
        *(ushort4*)(Ah + nd * AST + ko) = hi;
        *(ushort4*)(Al + nd * AST + ko) = lo;
    }
    int wr = (w >> 1) * 32, wc = (w & 1) * (KOUT / 2);
    int lrow = l & 15, lk = (l >> 4) * 8;
    f32x4 acc[2][CB];
#pragma unroll
    for (int rb = 0; rb < 2; ++rb)
#pragma unroll
        for (int cb = 0; cb < CB; ++cb) acc[rb][cb] = (f32x4){0.f, 0.f, 0.f, 0.f};
    for (int kt = 0; kt < KT; ++kt) {
        __syncthreads();
        for (int c = t; c < KOUT * 4; c += 256) {  // uint4 chunks of 8 bf16
            int col = c >> 2, ko = (c & 3) * 8;
            *(uint4*)(Wh + col * 40 + ko) =
                *(const uint4*)(wsplit + ((size_t)(kt * 2 + 0) * KOUT + col) * 32 + ko);
            *(uint4*)(Wl + col * 40 + ko) =
                *(const uint4*)(wsplit + ((size_t)(kt * 2 + 1) * KOUT + col) * 32 + ko);
        }
        __syncthreads();
        short8v ah0 = *(const short8v*)(Ah + (wr + lrow) * AST + kt * 32 + lk);
        short8v ah1 = *(const short8v*)(Ah + (wr + 16 + lrow) * AST + kt * 32 + lk);
        short8v al0 = *(const short8v*)(Al + (wr + lrow) * AST + kt * 32 + lk);
        short8v al1 = *(const short8v*)(Al + (wr + 16 + lrow) * AST + kt * 32 + lk);
#pragma unroll
        for (int cb = 0; cb < CB; ++cb) {
            int col = wc + cb * 16 + lrow;
            short8v bh = *(const short8v*)(Wh + col * 40 + lk);
            short8v bl = *(const short8v*)(Wl + col * 40 + lk);
            acc[0][cb] = __builtin_amdgcn_mfma_f32_16x16x32_bf16(ah0, bh, acc[0][cb], 0, 0, 0);
            acc[0][cb] = __builtin_amdgcn_mfma_f32_16x16x32_bf16(ah0, bl, acc[0][cb], 0, 0, 0);
            acc[0][cb] = __builtin_amdgcn_mfma_f32_16x16x32_bf16(al0, bh, acc[0][cb], 0, 0, 0);
            acc[1][cb] = __builtin_amdgcn_mfma_f32_16x16x32_bf16(ah1, bh, acc[1][cb], 0, 0, 0);
            acc[1][cb] = __builtin_amdgcn_mfma_f32_16x16x32_bf16(ah1, bl, acc[1][cb], 0, 0, 0);
            acc[1][cb] = __builtin_amdgcn_mfma_f32_16x16x32_bf16(al1, bh, acc[1][cb], 0, 0, 0);
        }
    }
#pragma unroll
    for (int rb = 0; rb < 2; ++rb) {
#pragma unroll
        for (int reg = 0; reg < 4; ++reg) {
            int row = wr + rb * 16 + (l >> 4) * 4 + reg;
            int node = base + row;
            if (node < n) {
                float sc = SCALE ? dis[node] : 1.0f;
                unsigned short* cr = C + (size_t)node * KOUT;
#pragma unroll
                for (int cb = 0; cb < CB; ++cb) {
                    int col = wc + cb * 16 + lrow;
                    cr[col] = f2bf(acc[rb][cb][reg] * sc);
                }
            }
        }
    }
}

// ---------------- GAT projection (32x32 MFMA) fused with a_src/a_dst dots ---------------
__global__ __launch_bounds__(256) void k_mm_gat(const float* __restrict__ A,
                                                const unsigned short* __restrict__ wsplit,
                                                unsigned short* __restrict__ C, int n,
                                                const float* __restrict__ wp,
                                                float* __restrict__ asrc,
                                                float* __restrict__ adst) {
    __shared__ unsigned short Ah[64 * 40];
    __shared__ unsigned short Al[64 * 40];
    __shared__ unsigned short Wh[32 * 40];
    __shared__ unsigned short Wl[32 * 40];
    __shared__ float gsh[64 * 33];
    int t = threadIdx.x;
    int l = t & 63, w = t >> 6;
    int base = blockIdx.x * 64;
#pragma unroll
    for (int p = 0; p < 2; ++p) {
        int c = p * 256 + t;  // 512 float4 chunks
        int nd = c >> 3, ko = (c & 7) * 4;
        int node = min(base + nd, n - 1);
        float4 v = *(const float4*)(A + (size_t)node * 32 + ko);
        ushort4 hi, lo;
        split4(v, hi, lo);
        *(ushort4*)(Ah + nd * 40 + ko) = hi;
        *(ushort4*)(Al + nd * 40 + ko) = lo;
    }
    if (t < 128) {  // 128 uint4 chunks per buffer
        int col = t >> 2, ko = (t & 3) * 8;
        *(uint4*)(Wh + col * 40 + ko) = *(const uint4*)(wsplit + ((size_t)col) * 32 + ko);
        *(uint4*)(Wl + col * 40 + ko) = *(const uint4*)(wsplit + ((size_t)(32 + col)) * 32 + ko);
    }
    __syncthreads();
    int wr = (w >> 1) * 32, wc = (w & 1) * 16;
    int lrow = l & 15, lk = (l >> 4) * 8;
    short8v ah0 = *(const short8v*)(Ah + (wr + lrow) * 40 + lk);
    short8v ah1 = *(const short8v*)(Ah + (wr + 16 + lrow) * 40 + lk);
    short8v al0 = *(const short8v*)(Al + (wr + lrow) * 40 + lk);
    short8v al1 = *(const short8v*)(Al + (wr + 16 + lrow) * 40 + lk);
    short8v bh = *(const short8v*)(Wh + (wc + lrow) * 40 + lk);
    short8v bl = *(const short8v*)(Wl + (wc + lrow) * 40 + lk);
    f32x4 acc0 = (f32x4){0.f, 0.f, 0.f, 0.f}, acc1 = (f32x4){0.f, 0.f, 0.f, 0.f};
    acc0 = __builtin_amdgcn_mfma_f32_16x16x32_bf16(ah0, bh, acc0, 0, 0, 0);
    acc0 = __builtin_amdgcn_mfma_f32_16x16x32_bf16(ah0, bl, acc0, 0, 0, 0);
    acc0 = __builtin_amdgcn_mfma_f32_16x16x32_bf16(al0, bh, acc0, 0, 0, 0);
    acc1 = __builtin_amdgcn_mfma_f32_16x16x32_bf16(ah1, bh, acc1, 0, 0, 0);
    acc1 = __builtin_amdgcn_mfma_f32_16x16x32_bf16(ah1, bl, acc1, 0, 0, 0);
    acc1 = __builtin_amdgcn_mfma_f32_16x16x32_bf16(al1, bh, acc1, 0, 0, 0);
#pragma unroll
    for (int rb = 0; rb < 2; ++rb) {
#pragma unroll
        for (int reg = 0; reg < 4; ++reg) {
            int row = wr + rb * 16 + (l >> 4) * 4 + reg;
            int node = base + row;
            float v = rb ? acc1[reg] : acc0[reg];
            unsigned short b16 = f2bf(v);
            gsh[row * 33 + wc + lrow] = __uint_as_float((unsigned)b16 << 16);
            if (node < n) C[(size_t)node * 32 + wc + lrow] = b16;
        }
    }
    __syncthreads();
    if (t < 64) {
        int node = base + t;
        float s = 0.f, d = 0.f;
#pragma unroll
        for (int c = 0; c < 32; ++c) {
            float gv = gsh[t * 33 + c];
            s += gv * wp[OFF_GAS + c];
            d += gv * wp[OFF_GAD + c];
        }
        if (node < n) { asrc[node] = s; adst[node] = d; }
    }
}

// F=64: half-wave per edge, explicit 4-batches
template <bool RELU>
__global__ void k_agg64(const unsigned* __restrict__ t, const int* __restrict__ rptr,
                        const int* __restrict__ csr_src, const float* __restrict__ dis,
                        const float* __restrict__ bias, float* __restrict__ out, int n) {
    int wave = (blockIdx.x * blockDim.x + threadIdx.x) >> 6;
    int lane = threadIdx.x & 63;
    if (wave >= n) return;
    int dst = wave;
    int half = lane >> 5, l32 = lane & 31;
    float dd = dis[dst];
    float ax = 0.f, ay = 0.f;
    if (!half) {
        unsigned u = t[(size_t)dst * 32 + l32];
        ax = lo_(u);
        ay = hi_(u);
    }
    int s = max(0, min(rptr[dst], EE));
    int e = max(s, min(rptr[dst + 1], EE));
    int cnt = e - s;
    int pairs = cnt >> 1;
    int p = 0;
    for (; p + 4 <= pairs; p += 4) {
        int jb = s + 2 * p + half;
        int i0 = csr_src[jb], i1 = csr_src[jb + 2], i2 = csr_src[jb + 4], i3 = csr_src[jb + 6];
        unsigned u0 = t[(size_t)i0 * 32 + l32], u1 = t[(size_t)i1 * 32 + l32];
        unsigned u2 = t[(size_t)i2 * 32 + l32], u3 = t[(size_t)i3 * 32 + l32];
        ax += (lo_(u0) + lo_(u1)) + (lo_(u2) + lo_(u3));
        ay += (hi_(u0) + hi_(u1)) + (hi_(u2) + hi_(u3));
    }
    for (; p < pairs; ++p) {
        int i0 = csr_src[s + 2 * p + half];
        unsigned u0 = t[(size_t)i0 * 32 + l32];
        ax += lo_(u0);
        ay += hi_(u0);
    }
    if ((cnt & 1) && !half) {
        unsigned u0 = t[(size_t)csr_src[e - 1] * 32 + l32];
        ax += lo_(u0);
        ay += hi_(u0);
    }
    ax += __shfl_down(ax, 32);
    ay += __shfl_down(ay, 32);
    if (!half) {
        float2 bv = *(const float2*)(bias + 2 * l32);
        float vx = ax * dd + bv.x;
        float vy = ay * dd + bv.y;
        if (RELU) { vx = fmaxf(vx, 0.f); vy = fmaxf(vy, 0.f); }
        *(float2*)(out + (size_t)dst * 64 + 2 * l32) = make_float2(vx, vy);
    }
}

// F=32: quarter-wave per edge, explicit 4-batches
template <bool RELU>
__global__ void k_agg32(const unsigned* __restrict__ t, const int* __restrict__ rptr,
                        const int* __restrict__ csr_src, const float* __restrict__ dis,
                        const float* __restrict__ bias, float* __restrict__ out, int n) {
    int wave = (blockIdx.x * blockDim.x + threadIdx.x) >> 6;
    int lane = threadIdx.x & 63;
    if (wave >= n) return;
    int dst = wave;
    int q = lane >> 4, l16 = lane & 15;
    float dd = dis[dst];
    float ax = 0.f, ay = 0.f;
    if (q == 0) {
        unsigned u = t[(size_t)dst * 16 + l16];
        ax = lo_(u);
        ay = hi_(u);
    }
    int s = max(0, min(rptr[dst], EE));
    int e = max(s, min(rptr[dst + 1], EE));
    int cnt = e - s;
    int quads = cnt >> 2;
    int p = 0;
    for (; p + 4 <= quads; p += 4) {
        int jb = s + 4 * p + q;
        int i0 = csr_src[jb], i1 = csr_src[jb + 4], i2 = csr_src[jb + 8], i3 = csr_src[jb + 12];
        unsigned u0 = t[(size_t)i0 * 16 + l16], u1 = t[(size_t)i1 * 16 + l16];
        unsigned u2 = t[(size_t)i2 * 16 + l16], u3 = t[(size_t)i3 * 16 + l16];
        ax += (lo_(u0) + lo_(u1)) + (lo_(u2) + lo_(u3));
        ay += (hi_(u0) + hi_(u1)) + (hi_(u2) + hi_(u3));
    }
    for (; p < quads; ++p) {
        int i0 = csr_src[s + 4 * p + q];
        unsigned u0 = t[(size_t)i0 * 16 + l16];
        ax += lo_(u0);
        ay += hi_(u0);
    }
    int rem = cnt - 4 * quads;
    if (q < rem) {
        unsigned u0 = t[(size_t)csr_src[s + 4 * quads + q] * 16 + l16];
        ax += lo_(u0);
        ay += hi_(u0);
    }
    ax += __shfl_down(ax, 32);
    ay += __shfl_down(ay, 32);
    ax += __shfl_down(ax, 16);
    ay += __shfl_down(ay, 16);
    if (q == 0) {
        float2 bv = *(const float2*)(bias + 2 * l16);
        float vx = ax * dd + bv.x;
        float vy = ay * dd + bv.y;
        if (RELU) { vx = fmaxf(vx, 0.f); vy = fmaxf(vy, 0.f); }
        *(float2*)(out + (size_t)dst * 32 + 2 * l16) = make_float2(vx, vy);
    }
}

// ---------------- GAT aggregation ----------------
__global__ void k_gat_agg(const unsigned* __restrict__ g, const int* __restrict__ rptr,
                          const int* __restrict__ csr_src, const float* __restrict__ asrc,
                          const float* __restrict__ adst, const float* __restrict__ gat_b,
                          float* __restrict__ out, int n) {
    int wave = (blockIdx.x * blockDim.x + threadIdx.x) >> 6;
    int lane = threadIdx.x & 63;
    if (wave >= n) return;
    int dst = wave;
    int q = lane >> 4, l16 = lane & 15;
    float ad = adst[dst];
    int s = max(0, min(rptr[dst], EE));
    int e = max(s, min(rptr[dst + 1], EE));
    float ax = 0.f, ay = 0.f, denom = 0.f;
    if (q == 0) {
        float w0 = __expf(fminf(leakyf_(asrc[dst] + ad), 80.f));
        unsigned u = g[(size_t)dst * 16 + l16];
        ax = lo_(u) * w0;
        ay = hi_(u) * w0;
        denom = w0;
    }
    int cnt = e - s;
    int quads = cnt >> 2;
    int p = 0;
    for (; p + 4 <= quads; p += 4) {
        int jb = s + 4 * p + q;
        int i0 = csr_src[jb], i1 = csr_src[jb + 4], i2 = csr_src[jb + 8], i3 = csr_src[jb + 12];
        float a0 = asrc[i0], a1 = asrc[i1], a2 = asrc[i2], a3 = asrc[i3];
        unsigned u0 = g[(size_t)i0 * 16 + l16], u1 = g[(size_t)i1 * 16 + l16];
        unsigned u2 = g[(size_t)i2 * 16 + l16], u3 = g[(size_t)i3 * 16 + l16];
        float w0 = __expf(fminf(leakyf_(a0 + ad), 80.f));
        float w1 = __expf(fminf(leakyf_(a1 + ad), 80.f));
        float w2 = __expf(fminf(leakyf_(a2 + ad), 80.f));
        float w3 = __expf(fminf(leakyf_(a3 + ad), 80.f));
        denom += (w0 + w1) + (w2 + w3);
        ax += lo_(u0) * w0 + lo_(u1) * w1 + lo_(u2) * w2 + lo_(u3) * w3;
        ay += hi_(u0) * w0 + hi_(u1) * w1 + hi_(u2) * w2 + hi_(u3) * w3;
    }
    for (; p < quads; ++p) {
        int i0 = csr_src[s + 4 * p + q];
        float wgt = __expf(fminf(leakyf_(asrc[i0] + ad), 80.f));
        unsigned u0 = g[(size_t)i0 * 16 + l16];
        denom += wgt;
        ax += lo_(u0) * wgt;
        ay += hi_(u0) * wgt;
    }
    int rem = cnt - 4 * quads;
    if (q < rem) {
        int i0 = csr_src[s + 4 * quads + q];
        float wgt = __expf(fminf(leakyf_(asrc[i0] + ad), 80.f));
        unsigned u0 = g[(size_t)i0 * 16 + l16];
        denom += wgt;
        ax += lo_(u0) * wgt;
        ay += hi_(u0) * wgt;
    }
    ax += __shfl_down(ax, 32);
    ay += __shfl_down(ay, 32);
    denom += __shfl_down(denom, 32);
    ax += __shfl_down(ax, 16);
    ay += __shfl_down(ay, 16);
    denom += __shfl_down(denom, 16);
    if (q == 0) {
        float r = rcp_(denom);
        float vx = fmaxf(ax * r + gat_b[2 * l16], 0.f);
        float vy = fmaxf(ay * r + gat_b[2 * l16 + 1], 0.f);
        *(float2*)(out + (size_t)dst * 32 + 2 * l16) = make_float2(vx, vy);
    }
}

// ---------------- fused LSTM gates (MFMA, both dirs) + BN + FC + output -----------------
__global__ __launch_bounds__(256) void k_lstm_full(const float* __restrict__ h,
                                                   const unsigned short* __restrict__ wsg,
                                                   const float* __restrict__ wp,
                                                   void* __restrict__ out,
                                                   const int* __restrict__ flags, int n) {
    __shared__ unsigned short Ah[64 * 40];   // 5.1 KB
    __shared__ unsigned short Al[64 * 40];   // 5.1 KB
    __shared__ unsigned short Wh[192 * 40];  // 15.4 KB (ps aliases this after MFMA)
    __shared__ unsigned short Wl[192 * 40];  // 15.4 KB
    __shared__ float rs[64 * 129];           // 33.0 KB
    __shared__ float bI[2][64], bG[2][64], bO[2][64], gsc[2][64], gbe[2][64];  // 2.5 KB
    float* ps = (float*)Wh;
    int t = threadIdx.x, l = t & 63, w = t >> 6;
    int base = blockIdx.x * 64;
    // stage h hi/lo
#pragma unroll
    for (int p = 0; p < 2; ++p) {
        int c = p * 256 + t, nd = c >> 3, ko = (c & 7) * 4;
        int node = min(base + nd, n - 1);
        float4 v = *(const float4*)(h + (size_t)node * 32 + ko);
        ushort4 hi, lo;
        split4(v, hi, lo);
        *(ushort4*)(Ah + nd * 40 + ko) = hi;
        *(ushort4*)(Al + nd * 40 + ko) = lo;
    }
    // biases / BN factors, both dirs
    if (t < 128) {
        int dir = t >> 6, j = t & 63;
        const float* bi_ = wp + (dir ? OFF_BIHB : OFF_BIHF);
        const float* bh_ = wp + (dir ? OFF_BHHB : OFF_BHHF);
        bI[dir][j] = bi_[j] + bh_[j];
        bG[dir][j] = bi_[128 + j] + bh_[128 + j];
        bO[dir][j] = bi_[192 + j] + bh_[192 + j];
        gsc[dir][j] = wp[OFF_GAMMA + dir * 64 + j] * rsqrtf(1.0f + 1e-5f);
        gbe[dir][j] = wp[OFF_BETA + dir * 64 + j];
    }
    // stage W dir0
    {
        const unsigned short* sh = wsg;
        const unsigned short* sl = wsg + (size_t)192 * 32;
#pragma unroll
        for (int p = 0; p < 3; ++p) {
            int c = p * 256 + t, row = c >> 2, ko = (c & 3) * 8;
            *(uint4*)(Wh + row * 40 + ko) = *(const uint4*)(sh + (size_t)row * 32 + ko);
            *(uint4*)(Wl + row * 40 + ko) = *(const uint4*)(sl + (size_t)row * 32 + ko);
        }
    }
    __syncthreads();
    int lrow = l & 15, lk = (l >> 4) * 8;
    short8v hh = *(const short8v*)(Ah + (w * 16 + lrow) * 40 + lk);
    short8v hl = *(const short8v*)(Al + (w * 16 + lrow) * 40 + lk);
    for (int dir = 0; dir < 2; ++dir) {
        if (dir == 1) {
            __syncthreads();  // dir0 MFMA done reading Wh/Wl
            const unsigned short* sh = wsg + (size_t)2 * 192 * 32;
            const unsigned short* sl = wsg + (size_t)3 * 192 * 32;
#pragma unroll
            for (int p = 0; p < 3; ++p) {
                int c = p * 256 + t, row = c >> 2, ko = (c & 3) * 8;
                *(uint4*)(Wh + row * 40 + ko) = *(const uint4*)(sh + (size_t)row * 32 + ko);
                *(uint4*)(Wl + row * 40 + ko) = *(const uint4*)(sl + (size_t)row * 32 + ko);
            }
            __syncthreads();
        }
        f32x4 acc[12];
#pragma unroll
        for (int m = 0; m < 12; ++m) acc[m] = (f32x4){0.f, 0.f, 0.f, 0.f};
#pragma unroll
        for (int m = 0; m < 12; ++m) {
            short8v wh_ = *(const short8v*)(Wh + (m * 16 + lrow) * 40 + lk);
            short8v wl_ = *(const short8v*)(Wl + (m * 16 + lrow) * 40 + lk);
            acc[m] = __builtin_amdgcn_mfma_f32_16x16x32_bf16(wh_, hh, acc[m], 0, 0, 0);
            acc[m] = __builtin_amdgcn_mfma_f32_16x16x32_bf16(wl_, hh, acc[m], 0, 0, 0);
            acc[m] = __builtin_amdgcn_mfma_f32_16x16x32_bf16(wh_, hl, acc[m], 0, 0, 0);
        }
#pragma unroll
        for (int m = 0; m < 4; ++m) {
#pragma unroll
            for (int reg = 0; reg < 4; ++reg) {
                int j = 16 * m + (l >> 4) * 4 + reg;
                float iv = acc[m][reg] + bI[dir][j];
                float gv = acc[m + 4][reg] + bG[dir][j];
                float ov = acc[m + 8][reg] + bO[dir][j];
                float v = sigmoidf_(ov) * tanhf_(sigmoidf_(iv) * tanhf_(gv));
                rs[(w * 16 + lrow) * 129 + dir * 64 + j] = v * gsc[dir][j] + gbe[dir][j];
            }
        }
    }
    __syncthreads();  // rs complete; Wh reads done -> ps alias safe
    {
        int nd = t & 63, quarter = t >> 6;
        const float* fcw = wp + OFF_FCW;
        int jbase = quarter * 32;
        float p10[10];
#pragma unroll
        for (int c = 0; c < 10; ++c) p10[c] = 0.f;
#pragma unroll 4
        for (int k = 0; k < 32; ++k) {
            float r = rs[nd * 129 + jbase + k];
#pragma unroll
            for (int c = 0; c < 10; ++c) p10[c] += r * fcw[c * 128 + jbase + k];
        }
#pragma unroll
        for (int c = 0; c < 10; ++c) ps[quarter * 640 + nd * 10 + c] = p10[c];
    }
    __syncthreads();
    bool f32o = flags[0] != 0;
    for (int idx = t; idx < 640; idx += 256) {
        int gnode = base + idx / 10;
        if (gnode < n) {
            int c = idx % 10;
            float v = wp[OFF_FCB + c] + ps[idx] + ps[640 + idx] + ps[1280 + idx] + ps[1920 + idx];
            if (f32o) ((float*)out)[(size_t)base * 10 + idx] = v;
            else ((unsigned short*)out)[(size_t)base * 10 + idx] = f2bf(v);
        }
    }
}

// ---------------- launch ----------------
extern "C" void kernel_launch(void* const* d_in, const int* in_sizes, int n_in,
                              void* d_out, int out_size, void* d_ws, size_t ws_size,
                              hipStream_t stream) {
    const int N = NN;

    char* w = (char*)d_ws;
    auto alloc = [&](size_t bytes) {
        void* p = (void*)w;
        w += (bytes + 255) & ~(size_t)255;
        return p;
    };
    int* flags = (int*)alloc(256);
    float* wpool = (float*)alloc((size_t)WTOTAL * 4);
    unsigned short* wsplit = (unsigned short*)alloc(65536);   // W1 hi/lo
    unsigned short* ws2 = (unsigned short*)alloc(32768);      // W2 hi/lo
    unsigned short* ws3 = (unsigned short*)alloc(8192);       // W3 hi/lo
    unsigned short* wsgat = (unsigned short*)alloc(4096);     // GATW hi/lo
    unsigned short* wsg = (unsigned short*)alloc(49152);      // LSTM gate W'' hi/lo
    float* dis = (float*)alloc((size_t)N * 4);
    int* rptr = (int*)alloc((size_t)(N + 1) * 4);
    int* csr_src = (int*)alloc((size_t)EE * 4);
    unsigned* gh = (unsigned*)alloc((size_t)NBK * 256 * 4);
    unsigned* gh2 = (unsigned*)alloc((size_t)NBK * 256 * 4);
    unsigned* bsum = (unsigned*)alloc(1024);
    int* bb = (int*)alloc(1024);
    int2* ebkt = (int2*)alloc((size_t)EE * 8);
    float* asrc = (float*)alloc((size_t)N * 4);
    float* adst = (float*)alloc((size_t)N * 4);
    unsigned* bufT = (unsigned*)alloc((size_t)N * 64 * 4);  // bf16 N x 128
    float* bufH = (float*)alloc((size_t)N * 128 * 4);       // fp32 N x 128

    WSrc ws_srcs;
    for (int i = 0; i < 20; ++i) ws_srcs.p[i] = d_in[2 + i];

    const int AGG = (N + 3) / 4;
    const int TMB = (N + 63) / 64;
    const int WB = (WTOTAL + 255) / 256;

    k_detect<<<1, 256, 0, stream>>>((const unsigned short*)d_in[0],
                                    (const unsigned int*)d_in[1], flags);
    k_cvt_w<<<WB, 256, 0, stream>>>(ws_srcs, wpool, flags, WTOTAL);
    k_prep_all<<<156, 256, 0, stream>>>(wpool, wsplit, ws2, ws3, wsgat, wsg);
    // bucketed CSR build
    k_hist<<<NBK, 256, 0, stream>>>(d_in[1], gh, flags);
    k_bscan_a<<<256, 256, 0, stream>>>(gh, gh2, bsum);
    k_bscan_b<<<1, 256, 0, stream>>>(bsum, bb, rptr);
    k_scatter<<<NBK, 256, 0, stream>>>(d_in[1], gh2, bb, ebkt, flags);
    k_bucket_csr<<<NBK, 256, 0, stream>>>(ebkt, bb, rptr, dis, csr_src);

    // GCN 1 (x -> t1' = (x@W1)*dis, bf16): MFMA for BOTH input dtypes (flag-gated)
    k_gcn1_mfma<0><<<TMB, 256, 0, stream>>>(d_in[0], wsplit, bufT, N, flags, dis);
    k_gcn1_mfma<1><<<TMB, 256, 0, stream>>>(d_in[0], wsplit, bufT, N, flags, dis);
    // GCN2 = fused agg128 + (h1@W2)*dis  (h1 never hits HBM)
    k_aggmm1<<<TMB, 512, 0, stream>>>(bufT, rptr, csr_src, dis, wpool + OFF_B1, ws2,
                                      (unsigned short*)bufT, N);
    k_agg64<true><<<AGG, 256, 0, stream>>>(bufT, rptr, csr_src, dis, wpool + OFF_B2, bufH, N);
    // GCN 3 (MFMA)
    k_mm_mfma<64, 32, true><<<TMB, 256, 0, stream>>>(bufH, ws3, (unsigned short*)bufT, N, dis);
    k_agg32<false><<<AGG, 256, 0, stream>>>(bufT, rptr, csr_src, dis, wpool + OFF_B3, bufH, N);
    // GAT projection fused with a_src/a_dst dots, then aggregation
    k_mm_gat<<<TMB, 256, 0, stream>>>(bufH, wsgat, (unsigned short*)bufT, N, wpool, asrc, adst);
    k_gat_agg<<<AGG, 256, 0, stream>>>(bufT, rptr, csr_src, asrc, adst, wpool + OFF_GAB, bufH, N);
    // fused LSTM gates (both dirs) + BN + FC + output
    k_lstm_full<<<TMB, 256, 0, stream>>>(bufH, wsg, wpool, d_out, flags, N);
}